// Round 2
// baseline (30767.316 us; speedup 1.0000x reference)
//
#include <hip/hip_runtime.h>
#include <hip/hip_bf16.h>
#include <stdint.h>

#define S_LEN 2048
#define BATCH 32
#define EDIM  512
#define HDIM  512
#define NSLICE 64      // workgroups per direction
#define SCOLS  8       // HDIM / NSLICE : h columns owned per WG
#define NG     24      // 3 gates * SCOLS rows of Wih/Whh per WG

typedef __attribute__((ext_vector_type(8))) short bf16x8;  // 8 bf16 = 4 VGPRs
typedef __attribute__((ext_vector_type(8))) float f32x8;
typedef __attribute__((ext_vector_type(4))) float f32x4;

__device__ __forceinline__ unsigned short f2bf(float f) {
    union { float f; unsigned int i; } v; v.f = f;
    unsigned int u = v.i;
    return (unsigned short)((u + 0x7fffu + ((u >> 16) & 1u)) >> 16);  // RNE
}
__device__ __forceinline__ bf16x8 cvt8(f32x8 v) {
    bf16x8 r;
#pragma unroll
    for (int i = 0; i < 8; ++i) r[i] = (short)f2bf(v[i]);
    return r;
}

// 128 WGs x 256 threads, all co-resident on 256 CUs (1 block/CU max -> no
// scheduling deadlock). Each WG: dir = wg>>6, slice = wg&63.
__global__ void __launch_bounds__(256, 1)
gru_persistent(const float* __restrict__ xseq,   // [S][B][E] fp32
               const float* __restrict__ Wih_f,
               const float* __restrict__ Whh_f,
               const float* __restrict__ bih_f,
               const float* __restrict__ bhh_f,
               const float* __restrict__ Wih_b,
               const float* __restrict__ Whh_b,
               const float* __restrict__ bih_b,
               const float* __restrict__ bhh_b,
               float* __restrict__ out,          // [B][2H] fp32
               int* __restrict__ flags,          // [2][64]
               unsigned short* __restrict__ h_buf) // [2 buf][2 dir][B][H] bf16
{
    const int wg   = blockIdx.x;
    const int dir  = wg >> 6;
    const int sl   = wg & 63;
    const int tid  = threadIdx.x;
    const int lane = tid & 63;
    const int wv   = tid >> 6;
    const int mt   = wv >> 1;   // M tile (batch 16-block) owned by this wave
    const int nt   = wv & 1;    // N tile (16 gate-cols) owned by this wave

    const float* Wih = dir ? Wih_b : Wih_f;
    const float* Whh = dir ? Whh_b : Whh_f;
    const float* bih = dir ? bih_b : bih_f;
    const float* bhh = dir ? bhh_b : bhh_f;

    __shared__ float gxl[BATCH][33];   // +1 pad vs 32 banks
    __shared__ float ghl[BATCH][33];
    __shared__ float hloc[BATCH][SCOLS];  // fp32 master copy of our h slice
    __shared__ float bih_s[NG], bhh_s[NG];

    // ---- persistent weight B-fragments in VGPRs (fp32 -> bf16 RNE once) ----
    // B-frag layout (16x16x32 bf16): n = lane&15, k = (lane>>4)*8 + j (j contig)
    bf16x8 wf[16], hf[16];   // Wih / Whh, one frag per 32-wide K tile
    {
        const int nl    = nt * 16 + (lane & 15);
        const int q8l   = (lane >> 4) * 8;
        const bool valid = (nl < NG);
        const int row = (nl >> 3) * HDIM + sl * SCOLS + (nl & 7); // gate*512 + col
#pragma unroll
        for (int kt = 0; kt < 16; ++kt) {
            bf16x8 a = {}; bf16x8 b = {};
            if (valid) {
                a = cvt8(*(const f32x8*)(Wih + (size_t)row * EDIM + kt * 32 + q8l));
                b = cvt8(*(const f32x8*)(Whh + (size_t)row * HDIM + kt * 32 + q8l));
            }
            wf[kt] = a; hf[kt] = b;
        }
    }
    if (tid < NG) {
        const int row = (tid >> 3) * HDIM + sl * SCOLS + (tid & 7);
        bih_s[tid] = bih[row];
        bhh_s[tid] = bhh[row];
    }
    hloc[tid >> 3][tid & 7] = 0.0f;   // h0 = 0
    __syncthreads();

    // A-frag addressing (16x16x32 bf16): m = lane&15, k = (lane>>4)*8 + j
    const int m_row = mt * 16 + (lane & 15);
    const int q8    = (lane >> 4) * 8;
    int* myflags = flags + dir * 64;

    const int b_pw = tid >> 3;   // pointwise thread -> (batch, col)
    const int c_pw = tid & 7;

    for (int t = 0; t < S_LEN; ++t) {
        // ---- gx = x[t] @ Wih^T : independent of h, runs before the sync ----
        const int tx = dir ? (S_LEN - 1 - t) : t;
        const float* xp = xseq + (size_t)tx * (BATCH * EDIM)
                          + (size_t)m_row * EDIM + q8;
        f32x4 accx = {0.f, 0.f, 0.f, 0.f};
#pragma unroll
        for (int kt = 0; kt < 16; ++kt) {
            bf16x8 a = cvt8(*(const f32x8*)(xp + kt * 32));
            accx = __builtin_amdgcn_mfma_f32_16x16x32_bf16(a, wf[kt], accx, 0, 0, 0);
        }

        // ---- wait until every slice of h(t-1) is published ----
        if (t > 0) {
            for (;;) {
                int f = __hip_atomic_load(&myflags[lane], __ATOMIC_RELAXED,
                                          __HIP_MEMORY_SCOPE_AGENT);
                if (__all(f >= t)) break;
            }
        }
        __builtin_amdgcn_fence(__ATOMIC_ACQUIRE, "agent");

        // ---- gh = h(t-1) @ Whh^T ----
        const unsigned short* hp = h_buf
            + ((size_t)((t & 1) * 2 + dir)) * (BATCH * HDIM)
            + (size_t)m_row * HDIM + q8;
        f32x4 acch = {0.f, 0.f, 0.f, 0.f};
#pragma unroll
        for (int kt = 0; kt < 16; ++kt) {
            bf16x8 a = *(const bf16x8*)(hp + kt * 32);
            acch = __builtin_amdgcn_mfma_f32_16x16x32_bf16(a, hf[kt], acch, 0, 0, 0);
        }

        // ---- C-layout (col=lane&15, row=(lane>>4)*4+j) -> LDS ----
        {
            const int n  = nt * 16 + (lane & 15);
            const int r0 = mt * 16 + (lane >> 4) * 4;
#pragma unroll
            for (int j = 0; j < 4; ++j) {
                gxl[r0 + j][n] = accx[j];
                ghl[r0 + j][n] = acch[j];
            }
        }
        __syncthreads();

        // ---- pointwise GRU cell, fp32, one thread per (b, c) ----
        {
            const float xr = gxl[b_pw][c_pw]      + bih_s[c_pw];
            const float hr = ghl[b_pw][c_pw]      + bhh_s[c_pw];
            const float xz = gxl[b_pw][8 + c_pw]  + bih_s[8 + c_pw];
            const float hz = ghl[b_pw][8 + c_pw]  + bhh_s[8 + c_pw];
            const float xn = gxl[b_pw][16 + c_pw] + bih_s[16 + c_pw];
            const float hn = ghl[b_pw][16 + c_pw] + bhh_s[16 + c_pw];
            const float r  = 1.f / (1.f + __expf(-(xr + hr)));
            const float z  = 1.f / (1.f + __expf(-(xz + hz)));
            const float pre = xn + r * hn;
            const float n_  = 2.f / (1.f + __expf(-2.f * pre)) - 1.f;  // tanh
            const float hnew = (1.f - z) * n_ + z * hloc[b_pw][c_pw];
            hloc[b_pw][c_pw] = hnew;
            if (t < S_LEN - 1) {
                h_buf[((size_t)(((t + 1) & 1) * 2 + dir)) * (BATCH * HDIM)
                      + (size_t)b_pw * HDIM + sl * SCOLS + c_pw] = f2bf(hnew);
            } else {
                out[(size_t)b_pw * (2 * HDIM) + dir * HDIM + sl * SCOLS + c_pw] = hnew;
            }
        }
        __syncthreads();   // drains vmem stores of all waves before publishing

        if (t < S_LEN - 1) {
            __builtin_amdgcn_fence(__ATOMIC_RELEASE, "agent");
            if (tid == 0) {
                __hip_atomic_store(&myflags[sl], t + 1, __ATOMIC_RELAXED,
                                   __HIP_MEMORY_SCOPE_AGENT);
            }
        }
    }
}

extern "C" void kernel_launch(void* const* d_in, const int* in_sizes, int n_in,
                              void* d_out, int out_size, void* d_ws, size_t ws_size,
                              hipStream_t stream) {
    // setup_inputs order: seq_length, embedding_seq, Wih_f, Whh_f, bih_f, bhh_f,
    //                     Wih_b, Whh_b, bih_b, bhh_b   (float32 tensors)
    const float* xseq  = (const float*)d_in[1];
    const float* Wih_f = (const float*)d_in[2];
    const float* Whh_f = (const float*)d_in[3];
    const float* bih_f = (const float*)d_in[4];
    const float* bhh_f = (const float*)d_in[5];
    const float* Wih_b = (const float*)d_in[6];
    const float* Whh_b = (const float*)d_in[7];
    const float* bih_b = (const float*)d_in[8];
    const float* bhh_b = (const float*)d_in[9];

    // ws layout: [0,512) flags int[2][64]; [512, 512+128K) h double buffers
    int* flags = (int*)d_ws;
    unsigned short* h_buf = (unsigned short*)((char*)d_ws + 512);
    const size_t init_bytes = 512 + (size_t)2 * 2 * BATCH * HDIM * sizeof(unsigned short);
    hipMemsetAsync(d_ws, 0, init_bytes, stream);   // zero flags + h0 (graph-safe)

    hipLaunchKernelGGL(gru_persistent, dim3(2 * NSLICE), dim3(256), 0, stream,
                       xseq, Wih_f, Whh_f, bih_f, bhh_f,
                       Wih_b, Whh_b, bih_b, bhh_b,
                       (float*)d_out, flags, h_buf);
}

// Round 3
// 14338.789 us; speedup vs baseline: 2.1457x; 2.1457x over previous
//
#include <hip/hip_runtime.h>
#include <hip/hip_bf16.h>
#include <stdint.h>

#define S_LEN 2048
#define BATCH 32
#define EDIM  512
#define HDIM  512
#define NSLICE 64      // workgroups per direction
#define SCOLS  8       // HDIM / NSLICE : h columns owned per WG
#define NG     24      // 3 gates * SCOLS rows of Wih/Whh per WG

typedef __attribute__((ext_vector_type(8))) short bf16x8;  // 8 bf16 = 4 VGPRs
typedef __attribute__((ext_vector_type(8))) float f32x8;
typedef __attribute__((ext_vector_type(4))) float f32x4;

__device__ __forceinline__ unsigned short f2bf(float f) {
    union { float f; unsigned int i; } v; v.f = f;
    unsigned int u = v.i;
    return (unsigned short)((u + 0x7fffu + ((u >> 16) & 1u)) >> 16);  // RNE
}
__device__ __forceinline__ bf16x8 cvt8(f32x8 v) {
    bf16x8 r;
#pragma unroll
    for (int i = 0; i < 8; ++i) r[i] = (short)f2bf(v[i]);
    return r;
}

// 128 WGs x 256 threads, all co-resident (1 block/CU). dir = wg>>6, slice = wg&63.
// Cross-WG h handoff is FENCE-FREE: all shared data moves with sc1 (agent /
// LLC-coherent) loads & stores, so no buffer_inv / buffer_wbl2 ever executes
// and the per-XCD L2s keep x / weights hot.
__global__ void __launch_bounds__(256, 1)
gru_persistent(const float* __restrict__ xseq,   // [S][B][E] fp32
               const float* __restrict__ Wih_f,
               const float* __restrict__ Whh_f,
               const float* __restrict__ bih_f,
               const float* __restrict__ bhh_f,
               const float* __restrict__ Wih_b,
               const float* __restrict__ Whh_b,
               const float* __restrict__ bih_b,
               const float* __restrict__ bhh_b,
               float* __restrict__ out,            // [B][2H] fp32
               int* __restrict__ flags,            // [2][64]
               unsigned short* __restrict__ h_buf) // [2 buf][2 dir][B][H] bf16
{
    const int wg   = blockIdx.x;
    const int dir  = wg >> 6;
    const int sl   = wg & 63;
    const int tid  = threadIdx.x;
    const int lane = tid & 63;
    const int wv   = tid >> 6;
    const int mt   = wv >> 1;   // M tile (batch 16-block) owned by this wave
    const int nt   = wv & 1;    // N tile (16 gate-cols) owned by this wave

    const float* Wih = dir ? Wih_b : Wih_f;
    const float* Whh = dir ? Whh_b : Whh_f;
    const float* bih = dir ? bih_b : bih_f;
    const float* bhh = dir ? bhh_b : bhh_f;

    __shared__ float gxl[BATCH][33];   // +1 pad vs 32 banks
    __shared__ float ghl[BATCH][33];
    __shared__ float hloc[BATCH][SCOLS];  // fp32 master copy of our h slice
    __shared__ float bih_s[NG], bhh_s[NG];

    // ---- persistent weight B-fragments in VGPRs (fp32 -> bf16 RNE once) ----
    // B-frag layout (16x16x32 bf16): n = lane&15, k = (lane>>4)*8 + j (j contig)
    bf16x8 wf[16], hf[16];   // Wih / Whh, one frag per 32-wide K tile
    {
        const int nl    = nt * 16 + (lane & 15);
        const int q8l   = (lane >> 4) * 8;
        const bool valid = (nl < NG);
        const int row = (nl >> 3) * HDIM + sl * SCOLS + (nl & 7); // gate*512 + col
#pragma unroll
        for (int kt = 0; kt < 16; ++kt) {
            bf16x8 a = {}; bf16x8 b = {};
            if (valid) {
                a = cvt8(*(const f32x8*)(Wih + (size_t)row * EDIM + kt * 32 + q8l));
                b = cvt8(*(const f32x8*)(Whh + (size_t)row * HDIM + kt * 32 + q8l));
            }
            wf[kt] = a; hf[kt] = b;
        }
    }
    if (tid < NG) {
        const int row = (tid >> 3) * HDIM + sl * SCOLS + (tid & 7);
        bih_s[tid] = bih[row];
        bhh_s[tid] = bhh[row];
    }
    hloc[tid >> 3][tid & 7] = 0.0f;   // h0 = 0
    __syncthreads();

    // A-frag addressing (16x16x32 bf16): m = lane&15, k = (lane>>4)*8 + j
    const int m_row = mt * 16 + (lane & 15);
    const int q8    = (lane >> 4) * 8;
    int* myflags = flags + dir * 64;

    const int b_pw = tid >> 3;   // pointwise thread -> (batch, col)
    const int c_pw = tid & 7;

    for (int t = 0; t < S_LEN; ++t) {
        // ---- gx = x[t] @ Wih^T : independent of h, overlaps the flag wait ----
        const int tx = dir ? (S_LEN - 1 - t) : t;
        const float* xp = xseq + (size_t)tx * (BATCH * EDIM)
                          + (size_t)m_row * EDIM + q8;
        f32x4 accx = {0.f, 0.f, 0.f, 0.f};
#pragma unroll
        for (int kt = 0; kt < 16; ++kt) {
            bf16x8 a = cvt8(*(const f32x8*)(xp + kt * 32));
            accx = __builtin_amdgcn_mfma_f32_16x16x32_bf16(a, wf[kt], accx, 0, 0, 0);
        }

        // ---- wait until every slice of h(t-1) is published (relaxed, sc1) ----
        if (t > 0) {
            for (;;) {
                int f = __hip_atomic_load(&myflags[lane], __ATOMIC_RELAXED,
                                          __HIP_MEMORY_SCOPE_AGENT);
                if (__all(f >= t)) break;
            }
        }

        // ---- load h(t-1) A-fragments straight from LLC (sc1), full ILP ----
        const unsigned short* hp = h_buf
            + ((size_t)((t & 1) * 2 + dir)) * (BATCH * HDIM)
            + (size_t)m_row * HDIM + q8;
        bf16x8 ha[16];
        asm volatile(
            "global_load_dwordx4 %0,  %16, off sc1\n\t"
            "global_load_dwordx4 %1,  %16, off offset:64  sc1\n\t"
            "global_load_dwordx4 %2,  %16, off offset:128 sc1\n\t"
            "global_load_dwordx4 %3,  %16, off offset:192 sc1\n\t"
            "global_load_dwordx4 %4,  %16, off offset:256 sc1\n\t"
            "global_load_dwordx4 %5,  %16, off offset:320 sc1\n\t"
            "global_load_dwordx4 %6,  %16, off offset:384 sc1\n\t"
            "global_load_dwordx4 %7,  %16, off offset:448 sc1\n\t"
            "global_load_dwordx4 %8,  %16, off offset:512 sc1\n\t"
            "global_load_dwordx4 %9,  %16, off offset:576 sc1\n\t"
            "global_load_dwordx4 %10, %16, off offset:640 sc1\n\t"
            "global_load_dwordx4 %11, %16, off offset:704 sc1\n\t"
            "global_load_dwordx4 %12, %16, off offset:768 sc1\n\t"
            "global_load_dwordx4 %13, %16, off offset:832 sc1\n\t"
            "global_load_dwordx4 %14, %16, off offset:896 sc1\n\t"
            "global_load_dwordx4 %15, %16, off offset:960 sc1\n\t"
            "s_waitcnt vmcnt(0)"
            : "=v"(ha[0]),  "=v"(ha[1]),  "=v"(ha[2]),  "=v"(ha[3]),
              "=v"(ha[4]),  "=v"(ha[5]),  "=v"(ha[6]),  "=v"(ha[7]),
              "=v"(ha[8]),  "=v"(ha[9]),  "=v"(ha[10]), "=v"(ha[11]),
              "=v"(ha[12]), "=v"(ha[13]), "=v"(ha[14]), "=v"(ha[15])
            : "v"(hp)
            : "memory");

        // ---- gh = h(t-1) @ Whh^T ----
        f32x4 acch = {0.f, 0.f, 0.f, 0.f};
#pragma unroll
        for (int kt = 0; kt < 16; ++kt) {
            acch = __builtin_amdgcn_mfma_f32_16x16x32_bf16(ha[kt], hf[kt], acch, 0, 0, 0);
        }

        // ---- C-layout (col=lane&15, row=(lane>>4)*4+j) -> LDS ----
        {
            const int n  = nt * 16 + (lane & 15);
            const int r0 = mt * 16 + (lane >> 4) * 4;
#pragma unroll
            for (int j = 0; j < 4; ++j) {
                gxl[r0 + j][n] = accx[j];
                ghl[r0 + j][n] = acch[j];
            }
        }
        __syncthreads();

        // ---- pointwise GRU cell, fp32, one thread per (b, c) ----
        {
            const float xr = gxl[b_pw][c_pw]      + bih_s[c_pw];
            const float hr = ghl[b_pw][c_pw]      + bhh_s[c_pw];
            const float xz = gxl[b_pw][8 + c_pw]  + bih_s[8 + c_pw];
            const float hz = ghl[b_pw][8 + c_pw]  + bhh_s[8 + c_pw];
            const float xn = gxl[b_pw][16 + c_pw] + bih_s[16 + c_pw];
            const float hn = ghl[b_pw][16 + c_pw] + bhh_s[16 + c_pw];
            const float r  = 1.f / (1.f + __expf(-(xr + hr)));
            const float z  = 1.f / (1.f + __expf(-(xz + hz)));
            const float pre = xn + r * hn;
            const float n_  = 2.f / (1.f + __expf(-2.f * pre)) - 1.f;  // tanh
            const float hnew = (1.f - z) * n_ + z * hloc[b_pw][c_pw];
            hloc[b_pw][c_pw] = hnew;
            if (t < S_LEN - 1) {
                // pair adjacent cols -> one dword sc1 (write-through to LLC)
                const float hother = __shfl_xor(hnew, 1);
                if ((c_pw & 1) == 0) {
                    unsigned int pack = (unsigned int)f2bf(hnew)
                                      | ((unsigned int)f2bf(hother) << 16);
                    unsigned int* dst = (unsigned int*)(h_buf
                        + ((size_t)(((t + 1) & 1) * 2 + dir)) * (BATCH * HDIM)
                        + (size_t)b_pw * HDIM + sl * SCOLS + c_pw);
                    asm volatile("global_store_dword %0, %1, off sc1"
                                 :: "v"(dst), "v"(pack) : "memory");
                }
            } else {
                out[(size_t)b_pw * (2 * HDIM) + dir * HDIM + sl * SCOLS + c_pw] = hnew;
            }
        }
        // drain our sc1 stores to the LLC before the barrier, then publish
        asm volatile("s_waitcnt vmcnt(0)" ::: "memory");
        __syncthreads();

        if (t < S_LEN - 1) {
            if (tid == 0) {
                __hip_atomic_store(&myflags[sl], t + 1, __ATOMIC_RELAXED,
                                   __HIP_MEMORY_SCOPE_AGENT);
            }
        }
    }
}

extern "C" void kernel_launch(void* const* d_in, const int* in_sizes, int n_in,
                              void* d_out, int out_size, void* d_ws, size_t ws_size,
                              hipStream_t stream) {
    // setup_inputs order: seq_length, embedding_seq, Wih_f, Whh_f, bih_f, bhh_f,
    //                     Wih_b, Whh_b, bih_b, bhh_b   (float32 tensors)
    const float* xseq  = (const float*)d_in[1];
    const float* Wih_f = (const float*)d_in[2];
    const float* Whh_f = (const float*)d_in[3];
    const float* bih_f = (const float*)d_in[4];
    const float* bhh_f = (const float*)d_in[5];
    const float* Wih_b = (const float*)d_in[6];
    const float* Whh_b = (const float*)d_in[7];
    const float* bih_b = (const float*)d_in[8];
    const float* bhh_b = (const float*)d_in[9];

    // ws layout: [0,512) flags int[2][64]; [512, 512+256K) h double buffers
    int* flags = (int*)d_ws;
    unsigned short* h_buf = (unsigned short*)((char*)d_ws + 512);
    const size_t init_bytes = 512 + (size_t)2 * 2 * BATCH * HDIM * sizeof(unsigned short);
    hipMemsetAsync(d_ws, 0, init_bytes, stream);   // zero flags + h0 (graph-safe)

    hipLaunchKernelGGL(gru_persistent, dim3(2 * NSLICE), dim3(256), 0, stream,
                       xseq, Wih_f, Whh_f, bih_f, bhh_f,
                       Wih_b, Whh_b, bih_b, bhh_b,
                       (float*)d_out, flags, h_buf);
}